// Round 2
// baseline (1396.474 us; speedup 1.0000x reference)
//
#include <hip/hip_runtime.h>

// CounterFlowNetwork fused kernel for MI355X (gfx950), round 2.
// Changes vs R1:
//  - W_eq/W_tr/W_ab column-slices held in VGPRs per wave (loaded once) —
//    removes ~5.6 GB of global B-fragment re-reads (R1 FETCH was 2.14 GB HBM).
//  - amdgpu_waves_per_eu(2,2): LDS (144KiB) limits us to 1 block/CU = 2 waves/EU
//    anyway; pinning it gives the register allocator the full 512-VGPR budget so
//    greg[8][16] + weight frags stay in registers (R1 spilled: VGPR_Count=128).
//  - Out tile staged in LDS and written as contiguous float4 (R1 WRITE 387 MB
//    for a 66 MB output: 64B store segments + write-allocate).
//  - Tiled-LDS transpose prep kernels (R1 preps ~80 µs from strided f32 reads).
//  - Sweep-0 ascending plate 8 skipped (g[8] unused until the final sweep).

typedef _Float16 f16;
typedef _Float16 f16x8 __attribute__((ext_vector_type(8)));
typedef float f32x4 __attribute__((ext_vector_type(4)));

#define TILE_B 32
#define NT 512
#define SLOT 16384            // one [32][256] f16 slot, bytes
#define TMPA_OFF 131072       // slot 8: shared activation tile
#define LDS_BYTES 147456      // 9 * 16384 = 144 KiB

__device__ __forceinline__ f32x4 mfma16(f16x8 a, f16x8 b, f32x4 c) {
  return __builtin_amdgcn_mfma_f32_16x16x32_f16(a, b, c, 0, 0, 0);
}
__device__ __forceinline__ f32x4 zero4() {
  f32x4 z; z[0] = 0.f; z[1] = 0.f; z[2] = 0.f; z[3] = 0.f; return z;
}
__device__ __forceinline__ float sigm(float s) { return 1.f / (1.f + __expf(-s)); }

// acc[fr][fc]: fr = row block (0..1), fc = col frag (w*32 + fc*16)
#define ACCQ(A, q) A[(q) >> 3][((q) >> 2) & 1][(q) & 3]

// A [32 x 256] f16 in LDS (row stride 512 B, XOR-swizzled); B fragments in regs.
__device__ __forceinline__ void gemm_regB(const char* aBase, const f16x8 (&B)[8][2],
                                          int lane, f32x4 (&acc)[2][2]) {
  const int l15 = lane & 15, kg = lane >> 4;
  const int sw = (l15 & 7) << 4;
  #pragma unroll
  for (int ks = 0; ks < 8; ++ks) {
    const int kk = (ks << 5) + (kg << 3);
    f16x8 a0 = *(const f16x8*)(aBase + l15 * 512 + ((kk * 2) ^ sw));
    f16x8 a1 = *(const f16x8*)(aBase + (16 + l15) * 512 + ((kk * 2) ^ sw));
    acc[0][0] = mfma16(a0, B[ks][0], acc[0][0]);
    acc[1][0] = mfma16(a1, B[ks][0], acc[1][0]);
    acc[0][1] = mfma16(a0, B[ks][1], acc[0][1]);
    acc[1][1] = mfma16(a1, B[ks][1], acc[1][1]);
  }
}

// A [32 x K] f16 in LDS (stride ASTRIDE); B = WT[n][K] f16 from global.
template <int K, int ASTRIDE>
__device__ __forceinline__ void gemm32(const char* aBase, const f16* __restrict__ WT,
                                       int w, int lane, f32x4 (&acc)[2][2]) {
  const int l15 = lane & 15, kg = lane >> 4;
  const int sw = (l15 & 7) << 4;
  #pragma unroll
  for (int ks = 0; ks < (K >> 5); ++ks) {
    const int kk = (ks << 5) + (kg << 3);
    f16x8 a0 = *(const f16x8*)(aBase + l15 * ASTRIDE + ((kk * 2) ^ sw));
    f16x8 a1 = *(const f16x8*)(aBase + (16 + l15) * ASTRIDE + ((kk * 2) ^ sw));
    f16x8 b0 = *(const f16x8*)(WT + (size_t)(w * 32 + l15) * K + kk);
    f16x8 b1 = *(const f16x8*)(WT + (size_t)(w * 32 + 16 + l15) * K + kk);
    acc[0][0] = mfma16(a0, b0, acc[0][0]);
    acc[1][0] = mfma16(a1, b0, acc[1][0]);
    acc[0][1] = mfma16(a0, b1, acc[0][1]);
    acc[1][1] = mfma16(a1, b1, acc[1][1]);
  }
}

// write 16 C-frag values as f16 into swizzled [32][256] LDS buffer
__device__ __forceinline__ void store16(char* buf, int w, int lane, const float* v) {
  const int l15 = lane & 15, kg = lane >> 4;
  #pragma unroll
  for (int q = 0; q < 16; ++q) {
    const int row = ((q >> 3) & 1) * 16 + kg * 4 + (q & 3);
    const int col = w * 32 + (((q >> 2) & 1) << 4) + l15;
    *(f16*)(buf + row * 512 + ((col * 2) ^ ((row & 7) << 4))) = (f16)v[q];
  }
}

// src [K][N] f32 -> dst [Npad][K] f16, tiled LDS transpose (coalesced both sides)
__global__ void prep_transpose(const float* __restrict__ src, f16* __restrict__ dst,
                               int K, int N, int Npad) {
  __shared__ float t[32][33];
  const int bk = blockIdx.x * 32, bn = blockIdx.y * 32;
  const int tx = threadIdx.x & 31, ty = threadIdx.x >> 5;  // 32 x 8
  #pragma unroll
  for (int i = 0; i < 32; i += 8) {
    const int k = bk + ty + i, n = bn + tx;
    t[ty + i][tx] = (k < K && n < N) ? src[(size_t)k * N + n] : 0.f;
  }
  __syncthreads();
  #pragma unroll
  for (int i = 0; i < 32; i += 8) {
    const int n = bn + ty + i, k = bk + tx;
    if (n < Npad && k < K) dst[(size_t)n * K + k] = (f16)t[tx][ty + i];
  }
}

__global__ __launch_bounds__(NT, 2) __attribute__((amdgpu_waves_per_eu(2, 2)))
void cfn_main(const float* __restrict__ x,
              const float* __restrict__ bge, const float* __restrict__ beq,
              const float* __restrict__ btr, const float* __restrict__ bab,
              const float* __restrict__ alphap,
              const float* __restrict__ b1p, const float* __restrict__ b2p,
              const f16* __restrict__ WgeT, const f16* __restrict__ WeqT,
              const f16* __restrict__ WtrT, const f16* __restrict__ WabT,
              const f16* __restrict__ W1T, const f16* __restrict__ W2T,
              float* __restrict__ out) {
  extern __shared__ char smem[];
  const int tid = threadIdx.x;
  const int lane = tid & 63;
  const int w = tid >> 6;
  const int l15 = lane & 15, kg = lane >> 4;
  const int r0 = blockIdx.x * TILE_B;
  const float alpha = alphap[0];
  const int colA = w * 32 + l15;
  const int colB = colA + 16;

  // hoisted per-lane biases (live across both sweeps)
  const float beq0 = beq[colA], beq1 = beq[colB];
  const float btr0 = btr[colA], btr1 = btr[colB];
  const float bab0 = bab[colA], bab1 = bab[colB];

  // ---- load W_eq/W_tr/W_ab column-slices into registers (once) ----
  f16x8 WeqR[8][2], WtrR[8][2], WabR[8][2];
  #pragma unroll
  for (int ks = 0; ks < 8; ++ks) {
    const int kk = (ks << 5) + (kg << 3);
    WeqR[ks][0] = *(const f16x8*)(WeqT + (size_t)colA * 256 + kk);
    WeqR[ks][1] = *(const f16x8*)(WeqT + (size_t)colB * 256 + kk);
    WtrR[ks][0] = *(const f16x8*)(WtrT + (size_t)colA * 256 + kk);
    WtrR[ks][1] = *(const f16x8*)(WtrT + (size_t)colB * 256 + kk);
    WabR[ks][0] = *(const f16x8*)(WabT + (size_t)colA * 256 + kk);
    WabR[ks][1] = *(const f16x8*)(WabT + (size_t)colB * 256 + kk);
  }

  // ---- stage x tile -> LDS f16 [32][512] swizzled (overlaps liquid slots 0..1)
  {
    const int row = tid >> 4;
    const int cb = (tid & 15) << 5;
    const int rs = (row & 7) << 4;
    const float* p = x + (size_t)(r0 + row) * 512 + cb;
    #pragma unroll
    for (int i = 0; i < 4; ++i) {
      float4 u = *(const float4*)(p + i * 8);
      float4 v = *(const float4*)(p + i * 8 + 4);
      f16x8 h;
      h[0] = (f16)u.x; h[1] = (f16)u.y; h[2] = (f16)u.z; h[3] = (f16)u.w;
      h[4] = (f16)v.x; h[5] = (f16)v.y; h[6] = (f16)v.z; h[7] = (f16)v.w;
      *(f16x8*)(smem + row * 1024 + (((cb + i * 8) * 2) ^ rs)) = h;
    }
  }
  __syncthreads();

  // ---- g0 = relu(x @ W_ge + b_ge)
  float greg[8][16];
  {
    f32x4 acc[2][2] = {{zero4(), zero4()}, {zero4(), zero4()}};
    gemm32<512, 1024>(smem, WgeT, w, lane, acc);
    const float bv0 = bge[colA], bv1 = bge[colB];
    #pragma unroll
    for (int q = 0; q < 16; ++q) {
      float v2 = ACCQ(acc, q) + (((q >> 2) & 1) ? bv1 : bv0);
      v2 = v2 > 0.f ? v2 : 0.f;
      #pragma unroll
      for (int s = 0; s < 8; ++s) greg[s][q] = v2;
    }
  }
  __syncthreads();  // x reads done; area becomes liquid slots

  float G8[16];

  #pragma unroll 1
  for (int sweep = 0; sweep < 2; ++sweep) {
    // ================= descending liquid sweep: n = 8..1 =================
    #pragma unroll 1
    for (int n = 8; n >= 1; --n) {
      float Gv[16];
      switch (n) {
        case 1: { _Pragma("unroll") for (int q = 0; q < 16; ++q) Gv[q] = greg[0][q]; } break;
        case 2: { _Pragma("unroll") for (int q = 0; q < 16; ++q) Gv[q] = greg[1][q]; } break;
        case 3: { _Pragma("unroll") for (int q = 0; q < 16; ++q) Gv[q] = greg[2][q]; } break;
        case 4: { _Pragma("unroll") for (int q = 0; q < 16; ++q) Gv[q] = greg[3][q]; } break;
        case 5: { _Pragma("unroll") for (int q = 0; q < 16; ++q) Gv[q] = greg[4][q]; } break;
        case 6: { _Pragma("unroll") for (int q = 0; q < 16; ++q) Gv[q] = greg[5][q]; } break;
        case 7: { _Pragma("unroll") for (int q = 0; q < 16; ++q) Gv[q] = greg[6][q]; } break;
        default: { _Pragma("unroll") for (int q = 0; q < 16; ++q) Gv[q] = greg[7][q]; } break;
      }
      float DF[16];
      if (n == 8) {
        const float e0 = sigm(beq0), e1 = sigm(beq1);
        #pragma unroll
        for (int q = 0; q < 16; ++q) DF[q] = Gv[q] - (((q >> 2) & 1) ? e1 : e0);
      } else {
        f32x4 acc[2][2] = {{zero4(), zero4()}, {zero4(), zero4()}};
        gemm_regB(smem + n * SLOT, WeqR, lane, acc);
        #pragma unroll
        for (int q = 0; q < 16; ++q)
          DF[q] = Gv[q] - sigm(ACCQ(acc, q) + (((q >> 2) & 1) ? beq1 : beq0));
      }
      // tmpA free: guaranteed by previous plate's trailing barrier
      store16(smem + TMPA_OFF, w, lane, DF);
      __syncthreads();
      float DEL[16];
      {
        f32x4 acc[2][2] = {{zero4(), zero4()}, {zero4(), zero4()}};
        gemm_regB(smem + TMPA_OFF, WtrR, lane, acc);
        #pragma unroll
        for (int q = 0; q < 16; ++q)
          DEL[q] = alpha * (ACCQ(acc, q) + (((q >> 2) & 1) ? btr1 : btr0));
      }
      __syncthreads();                       // tr readers of tmpA done
      store16(smem + TMPA_OFF, w, lane, DEL);
      __syncthreads();
      {
        f32x4 acc[2][2] = {{zero4(), zero4()}, {zero4(), zero4()}};
        gemm_regB(smem + TMPA_OFF, WabR, lane, acc);
        char* dst = smem + (n - 1) * SLOT;
        const char* prv = smem + n * SLOT;   // l[n+1] (unused when n==8)
        #pragma unroll
        for (int q = 0; q < 16; ++q) {
          const int row = ((q >> 3) & 1) * 16 + kg * 4 + (q & 3);
          const int col = ((q >> 2) & 1) ? colB : colA;
          const int off = row * 512 + ((col * 2) ^ ((row & 7) << 4));
          float lp = 0.f;
          if (n < 8) lp = (float)(*(const f16*)(prv + off));
          *(f16*)(dst + off) = (f16)(lp + ACCQ(acc, q) + (((q >> 2) & 1) ? bab1 : bab0));
        }
      }
      __syncthreads();                       // l[n] visible; tmpA readers done
    }
    // ================= ascending gas sweep =================
    const int nmax = (sweep == 0) ? 7 : 8;   // sweep-0 g[8] is dead
    #pragma unroll 1
    for (int n = 1; n <= nmax; ++n) {
      float Gv[16];
      switch (n) {
        case 1: { _Pragma("unroll") for (int q = 0; q < 16; ++q) Gv[q] = greg[0][q]; } break;
        case 2: { _Pragma("unroll") for (int q = 0; q < 16; ++q) Gv[q] = greg[1][q]; } break;
        case 3: { _Pragma("unroll") for (int q = 0; q < 16; ++q) Gv[q] = greg[2][q]; } break;
        case 4: { _Pragma("unroll") for (int q = 0; q < 16; ++q) Gv[q] = greg[3][q]; } break;
        case 5: { _Pragma("unroll") for (int q = 0; q < 16; ++q) Gv[q] = greg[4][q]; } break;
        case 6: { _Pragma("unroll") for (int q = 0; q < 16; ++q) Gv[q] = greg[5][q]; } break;
        case 7: { _Pragma("unroll") for (int q = 0; q < 16; ++q) Gv[q] = greg[6][q]; } break;
        default: { _Pragma("unroll") for (int q = 0; q < 16; ++q) Gv[q] = greg[7][q]; } break;
      }
      float DF[16];
      {
        f32x4 acc[2][2] = {{zero4(), zero4()}, {zero4(), zero4()}};
        gemm_regB(smem + (n - 1) * SLOT, WeqR, lane, acc);
        #pragma unroll
        for (int q = 0; q < 16; ++q)
          DF[q] = Gv[q] - sigm(ACCQ(acc, q) + (((q >> 2) & 1) ? beq1 : beq0));
      }
      if (n > 1) __syncthreads();            // previous plate's tr readers done
      store16(smem + TMPA_OFF, w, lane, DF);
      __syncthreads();
      float DEL[16];
      {
        f32x4 acc[2][2] = {{zero4(), zero4()}, {zero4(), zero4()}};
        gemm_regB(smem + TMPA_OFF, WtrR, lane, acc);
        #pragma unroll
        for (int q = 0; q < 16; ++q)
          DEL[q] = alpha * (ACCQ(acc, q) + (((q >> 2) & 1) ? btr1 : btr0));
      }
      if (n < 8) {
        switch (n) {
          case 1: { _Pragma("unroll") for (int q = 0; q < 16; ++q) greg[1][q] = Gv[q] - DEL[q]; } break;
          case 2: { _Pragma("unroll") for (int q = 0; q < 16; ++q) greg[2][q] = Gv[q] - DEL[q]; } break;
          case 3: { _Pragma("unroll") for (int q = 0; q < 16; ++q) greg[3][q] = Gv[q] - DEL[q]; } break;
          case 4: { _Pragma("unroll") for (int q = 0; q < 16; ++q) greg[4][q] = Gv[q] - DEL[q]; } break;
          case 5: { _Pragma("unroll") for (int q = 0; q < 16; ++q) greg[5][q] = Gv[q] - DEL[q]; } break;
          case 6: { _Pragma("unroll") for (int q = 0; q < 16; ++q) greg[6][q] = Gv[q] - DEL[q]; } break;
          default: { _Pragma("unroll") for (int q = 0; q < 16; ++q) greg[7][q] = Gv[q] - DEL[q]; } break;
        }
      } else {
        #pragma unroll
        for (int q = 0; q < 16; ++q) G8[q] = Gv[q] - DEL[q];
      }
    }
    __syncthreads();                         // asc tr readers done (sweep boundary)
  }

  // ---- head: feats = [g8 | l1] ----
  store16(smem + TMPA_OFF, w, lane, G8);     // tmpA free per loop-exit barrier
  __syncthreads();
  {
    f32x4 acc[2][2] = {{zero4(), zero4()}, {zero4(), zero4()}};
    const int sw = (l15 & 7) << 4;
    #pragma unroll
    for (int ks = 0; ks < 16; ++ks) {
      const int kk = (ks << 5) + (kg << 3);
      const char* base = (kk < 256) ? (smem + TMPA_OFF) : smem;  // g8 | l[1]
      const int kl = (kk < 256) ? kk : (kk - 256);
      f16x8 a0 = *(const f16x8*)(base + l15 * 512 + ((kl * 2) ^ sw));
      f16x8 a1 = *(const f16x8*)(base + (16 + l15) * 512 + ((kl * 2) ^ sw));
      f16x8 b0 = *(const f16x8*)(W1T + (size_t)colA * 512 + kk);
      f16x8 b1 = *(const f16x8*)(W1T + (size_t)colB * 512 + kk);
      acc[0][0] = mfma16(a0, b0, acc[0][0]);
      acc[1][0] = mfma16(a1, b0, acc[1][0]);
      acc[0][1] = mfma16(a0, b1, acc[0][1]);
      acc[1][1] = mfma16(a1, b1, acc[1][1]);
    }
    const float bv0 = b1p[colA], bv1 = b1p[colB];
    float H[16];
    #pragma unroll
    for (int q = 0; q < 16; ++q) {
      float v2 = ACCQ(acc, q) + (((q >> 2) & 1) ? bv1 : bv0);
      H[q] = v2 > 0.f ? v2 : 0.f;
    }
    store16(smem + SLOT, w, lane, H);        // slot1 (disjoint from GEMM1 reads)
  }
  __syncthreads();

  // ---- out = h @ W2 + b2 into registers (63 col-frags over 8 waves) ----
  f32x4 cf0[8], cf1[8];
  {
    const int sw = (l15 & 7) << 4;
    #pragma unroll
    for (int fi = 0; fi < 8; ++fi) {
      const int f = w + fi * 8;
      cf0[fi] = zero4(); cf1[fi] = zero4();
      if (f < 63) {
        #pragma unroll
        for (int ks = 0; ks < 8; ++ks) {
          const int kk = (ks << 5) + (kg << 3);
          f16x8 a0 = *(const f16x8*)(smem + SLOT + l15 * 512 + ((kk * 2) ^ sw));
          f16x8 a1 = *(const f16x8*)(smem + SLOT + (16 + l15) * 512 + ((kk * 2) ^ sw));
          f16x8 b = *(const f16x8*)(W2T + (size_t)(f * 16 + l15) * 256 + kk);
          cf0[fi] = mfma16(a0, b, cf0[fi]);
          cf1[fi] = mfma16(a1, b, cf1[fi]);
        }
      }
    }
  }
  __syncthreads();  // all reads of slot1 done; slots 0..7 become out staging

  // ---- stage out tile [32][1000] f32 in LDS, then coalesced copy ----
  {
    float* ob = (float*)smem;
    #pragma unroll
    for (int fi = 0; fi < 8; ++fi) {
      const int f = w + fi * 8;
      const int col = f * 16 + l15;
      if (f < 63 && col < 1000) {
        const float bv = b2p[col];
        #pragma unroll
        for (int j = 0; j < 4; ++j) {
          ob[(kg * 4 + j) * 1000 + col] = cf0[fi][j] + bv;
          ob[(16 + kg * 4 + j) * 1000 + col] = cf1[fi][j] + bv;
        }
      }
    }
  }
  __syncthreads();
  {
    const float* ob = (const float*)smem;
    float* op = out + (size_t)r0 * 1000;
    #pragma unroll 1
    for (int i = tid; i < 8000; i += NT) {
      float4 v = *(const float4*)(ob + i * 4);
      *(float4*)(op + i * 4) = v;
    }
  }
}

extern "C" void kernel_launch(void* const* d_in, const int* in_sizes, int n_in,
                              void* d_out, int out_size, void* d_ws, size_t ws_size,
                              hipStream_t stream) {
  const float* x   = (const float*)d_in[0];
  const float* Wge = (const float*)d_in[1];
  const float* bge = (const float*)d_in[2];
  const float* Weq = (const float*)d_in[3];
  const float* beq = (const float*)d_in[4];
  const float* Wtr = (const float*)d_in[5];
  const float* btr = (const float*)d_in[6];
  const float* Wab = (const float*)d_in[7];
  const float* bab = (const float*)d_in[8];
  const float* alp = (const float*)d_in[9];
  const float* W1  = (const float*)d_in[10];
  const float* b1  = (const float*)d_in[11];
  const float* W2  = (const float*)d_in[12];
  const float* b2  = (const float*)d_in[13];
  float* out = (float*)d_out;

  char* ws = (char*)d_ws;
  f16* WgeT = (f16*)(ws + 0);        // 256 x 512
  f16* WeqT = (f16*)(ws + 262144);   // 256 x 256
  f16* WtrT = (f16*)(ws + 393216);   // 256 x 256
  f16* WabT = (f16*)(ws + 524288);   // 256 x 256
  f16* W1T  = (f16*)(ws + 655360);   // 256 x 512
  f16* W2T  = (f16*)(ws + 917504);   // 1008 x 256 (rows >=1000 zero)

  prep_transpose<<<dim3(16, 8), 256, 0, stream>>>(Wge, WgeT, 512, 256, 256);
  prep_transpose<<<dim3(8, 8), 256, 0, stream>>>(Weq, WeqT, 256, 256, 256);
  prep_transpose<<<dim3(8, 8), 256, 0, stream>>>(Wtr, WtrT, 256, 256, 256);
  prep_transpose<<<dim3(8, 8), 256, 0, stream>>>(Wab, WabT, 256, 256, 256);
  prep_transpose<<<dim3(16, 8), 256, 0, stream>>>(W1, W1T, 512, 256, 256);
  prep_transpose<<<dim3(8, 32), 256, 0, stream>>>(W2, W2T, 256, 1000, 1008);

  (void)hipFuncSetAttribute(reinterpret_cast<const void*>(cfn_main),
                            hipFuncAttributeMaxDynamicSharedMemorySize, LDS_BYTES);
  cfn_main<<<16384 / TILE_B, NT, LDS_BYTES, stream>>>(
      x, bge, beq, btr, bab, alp, b1, b2,
      WgeT, WeqT, WtrT, WabT, W1T, W2T, out);
}

// Round 3
// 1085.057 us; speedup vs baseline: 1.2870x; 1.2870x over previous
//
#include <hip/hip_runtime.h>

// CounterFlowNetwork fused kernel for MI355X (gfx950), round 3.
// R1/R2 post-mortem: both rounds spilled (arch-VGPR budget pinned at 128;
// greg[8][16] f32 alone = 128 regs; R2's +192 weight regs made it worse —
// WRITE_SIZE 1.83 GB of scratch). Scratch streams also evicted the 1.4 MB
// weight set from L2 (R1's 1.8 GB weight misses).
// R3: fit in 128 arch VGPRs. Gas state packed f16 (64 regs), weights read
// from global via hoisted per-lane pointers (L2-resident once spills gone),
// dual LDS tmp buffers (fewer barriers), LDS = 160 KB.

typedef _Float16 f16;
typedef _Float16 f16x2 __attribute__((ext_vector_type(2)));
typedef _Float16 f16x8 __attribute__((ext_vector_type(8)));
typedef float f32x4 __attribute__((ext_vector_type(4)));

#define TILE_B 32
#define NT 512
#define SLOT 16384            // one [32][256] f16 slot, bytes
#define TMPA_OFF 131072       // DF tile
#define TMPB_OFF 147456       // DEL tile
#define LDS_BYTES 163840      // 160 KiB (8 liquid slots + tmpA + tmpB)

__device__ __forceinline__ f32x4 mfma16(f16x8 a, f16x8 b, f32x4 c) {
  return __builtin_amdgcn_mfma_f32_16x16x32_f16(a, b, c, 0, 0, 0);
}
__device__ __forceinline__ f32x4 zero4() {
  f32x4 z; z[0] = 0.f; z[1] = 0.f; z[2] = 0.f; z[3] = 0.f; return z;
}
__device__ __forceinline__ float sigm(float s) { return 1.f / (1.f + __expf(-s)); }

// acc[fr][fc]: fr = row block (0..1), fc = col frag (w*32 + fc*16)
#define ACCQ(A, q) A[(q) >> 3][((q) >> 2) & 1][(q) & 3]

// packed-gas accessors (S must be a compile-time constant at each use site)
#define GH_READ(S, Gv)  { _Pragma("unroll") for (int q = 0; q < 16; ++q) (Gv)[q] = (float)gh[S][q >> 1][q & 1]; }
#define GH_WRITE(S, V)  { _Pragma("unroll") for (int q = 0; q < 16; ++q) gh[S][q >> 1][q & 1] = (f16)((V)[q]); }

// A [32 x K] f16 in LDS (row stride ASTRIDE bytes, XOR-swizzled);
// B from global via per-lane row pointers pA/pB (pre-offset by +kg*8).
template <int K, int ASTRIDE>
__device__ __forceinline__ void gemmG(const char* aBase,
                                      const f16* __restrict__ pA,
                                      const f16* __restrict__ pB,
                                      int lane, f32x4 (&acc)[2][2]) {
  const int l15 = lane & 15, kg = lane >> 4;
  const int sw = (l15 & 7) << 4;
  #pragma unroll
  for (int ks = 0; ks < (K >> 5); ++ks) {
    const int kk = (ks << 5) + (kg << 3);
    f16x8 a0 = *(const f16x8*)(aBase + l15 * ASTRIDE + ((kk * 2) ^ sw));
    f16x8 a1 = *(const f16x8*)(aBase + (16 + l15) * ASTRIDE + ((kk * 2) ^ sw));
    f16x8 b0 = *(const f16x8*)(pA + (ks << 5));
    f16x8 b1 = *(const f16x8*)(pB + (ks << 5));
    acc[0][0] = mfma16(a0, b0, acc[0][0]);
    acc[1][0] = mfma16(a1, b0, acc[1][0]);
    acc[0][1] = mfma16(a0, b1, acc[0][1]);
    acc[1][1] = mfma16(a1, b1, acc[1][1]);
  }
}

// write 16 C-frag values as f16 into swizzled [32][256] LDS buffer
__device__ __forceinline__ void store16(char* buf, int w, int lane, const float* v) {
  const int l15 = lane & 15, kg = lane >> 4;
  #pragma unroll
  for (int q = 0; q < 16; ++q) {
    const int row = ((q >> 3) & 1) * 16 + kg * 4 + (q & 3);
    const int col = w * 32 + (((q >> 2) & 1) << 4) + l15;
    *(f16*)(buf + row * 512 + ((col * 2) ^ ((row & 7) << 4))) = (f16)v[q];
  }
}

// src [K][N] f32 -> dst [Npad][K] f16, tiled LDS transpose (coalesced both sides)
__global__ void prep_transpose(const float* __restrict__ src, f16* __restrict__ dst,
                               int K, int N, int Npad) {
  __shared__ float t[32][33];
  const int bk = blockIdx.x * 32, bn = blockIdx.y * 32;
  const int tx = threadIdx.x & 31, ty = threadIdx.x >> 5;  // 32 x 8
  #pragma unroll
  for (int i = 0; i < 32; i += 8) {
    const int k = bk + ty + i, n = bn + tx;
    t[ty + i][tx] = (k < K && n < N) ? src[(size_t)k * N + n] : 0.f;
  }
  __syncthreads();
  #pragma unroll
  for (int i = 0; i < 32; i += 8) {
    const int n = bn + ty + i, k = bk + tx;
    if (n < Npad && k < K) dst[(size_t)n * K + k] = (f16)t[tx][ty + i];
  }
}

__global__ __launch_bounds__(NT, 2)
void cfn_main(const float* __restrict__ x,
              const float* __restrict__ bge, const float* __restrict__ beq,
              const float* __restrict__ btr, const float* __restrict__ bab,
              const float* __restrict__ alphap,
              const float* __restrict__ b1p, const float* __restrict__ b2p,
              const f16* __restrict__ WgeT, const f16* __restrict__ WeqT,
              const f16* __restrict__ WtrT, const f16* __restrict__ WabT,
              const f16* __restrict__ W1T, const f16* __restrict__ W2T,
              float* __restrict__ out) {
  extern __shared__ char smem[];
  const int tid = threadIdx.x;
  const int lane = tid & 63;
  const int w = tid >> 6;
  const int l15 = lane & 15, kg = lane >> 4;
  const int r0 = blockIdx.x * TILE_B;
  const float alpha = alphap[0];
  const int colA = w * 32 + l15;
  const int colB = colA + 16;

  // per-lane biases (small, live across both sweeps)
  const float beq0 = beq[colA], beq1 = beq[colB];
  const float btr0 = btr[colA], btr1 = btr[colB];
  const float bab0 = bab[colA], bab1 = bab[colB];

  // hoisted per-lane B row pointers (include +kg*8 so inner offsets are imm)
  const f16* weqA = WeqT + (size_t)colA * 256 + kg * 8;
  const f16* weqB = WeqT + (size_t)colB * 256 + kg * 8;
  const f16* wtrA = WtrT + (size_t)colA * 256 + kg * 8;
  const f16* wtrB = WtrT + (size_t)colB * 256 + kg * 8;
  const f16* wabA = WabT + (size_t)colA * 256 + kg * 8;
  const f16* wabB = WabT + (size_t)colB * 256 + kg * 8;

  // ---- stage x tile -> LDS f16 [32][512] swizzled (overlaps liquid slots 0..1)
  {
    const int row = tid >> 4;
    const int cb = (tid & 15) << 5;
    const int rs = (row & 7) << 4;
    const float* p = x + (size_t)(r0 + row) * 512 + cb;
    #pragma unroll
    for (int i = 0; i < 4; ++i) {
      float4 u = *(const float4*)(p + i * 8);
      float4 v = *(const float4*)(p + i * 8 + 4);
      f16x8 h;
      h[0] = (f16)u.x; h[1] = (f16)u.y; h[2] = (f16)u.z; h[3] = (f16)u.w;
      h[4] = (f16)v.x; h[5] = (f16)v.y; h[6] = (f16)v.z; h[7] = (f16)v.w;
      *(f16x8*)(smem + row * 1024 + (((cb + i * 8) * 2) ^ rs)) = h;
    }
  }
  __syncthreads();

  // ---- g0 = relu(x @ W_ge + b_ge) -> packed f16 gas slots 0..7
  f16x2 gh[8][8];
  {
    f32x4 acc[2][2] = {{zero4(), zero4()}, {zero4(), zero4()}};
    const f16* wgeA = WgeT + (size_t)colA * 512 + kg * 8;
    const f16* wgeB = WgeT + (size_t)colB * 512 + kg * 8;
    gemmG<512, 1024>(smem, wgeA, wgeB, lane, acc);
    const float bv0 = bge[colA], bv1 = bge[colB];
    #pragma unroll
    for (int q = 0; q < 16; ++q) {
      float v2 = ACCQ(acc, q) + (((q >> 2) & 1) ? bv1 : bv0);
      v2 = v2 > 0.f ? v2 : 0.f;
      const f16 hv = (f16)v2;
      #pragma unroll
      for (int s = 0; s < 8; ++s) gh[s][q >> 1][q & 1] = hv;
    }
  }
  __syncthreads();  // x reads done; area becomes liquid slots

  float G8[16];

  #pragma unroll 1
  for (int sweep = 0; sweep < 2; ++sweep) {
    // ================= descending liquid sweep: n = 8..1 =================
    #pragma unroll 1
    for (int n = 8; n >= 1; --n) {
      float Gv[16];
      switch (n) {
        case 1: GH_READ(0, Gv); break;
        case 2: GH_READ(1, Gv); break;
        case 3: GH_READ(2, Gv); break;
        case 4: GH_READ(3, Gv); break;
        case 5: GH_READ(4, Gv); break;
        case 6: GH_READ(5, Gv); break;
        case 7: GH_READ(6, Gv); break;
        default: GH_READ(7, Gv); break;
      }
      float DF[16];
      if (n == 8) {
        const float e0 = sigm(beq0), e1 = sigm(beq1);
        #pragma unroll
        for (int q = 0; q < 16; ++q) DF[q] = Gv[q] - (((q >> 2) & 1) ? e1 : e0);
      } else {
        f32x4 acc[2][2] = {{zero4(), zero4()}, {zero4(), zero4()}};
        gemmG<256, 512>(smem + n * SLOT, weqA, weqB, lane, acc);
        #pragma unroll
        for (int q = 0; q < 16; ++q)
          DF[q] = Gv[q] - sigm(ACCQ(acc, q) + (((q >> 2) & 1) ? beq1 : beq0));
      }
      store16(smem + TMPA_OFF, w, lane, DF);   // prev tr-readers done (prev syncs)
      __syncthreads();                         // sync1: DF visible
      float DEL[16];
      {
        f32x4 acc[2][2] = {{zero4(), zero4()}, {zero4(), zero4()}};
        gemmG<256, 512>(smem + TMPA_OFF, wtrA, wtrB, lane, acc);
        #pragma unroll
        for (int q = 0; q < 16; ++q)
          DEL[q] = alpha * (ACCQ(acc, q) + (((q >> 2) & 1) ? btr1 : btr0));
      }
      store16(smem + TMPB_OFF, w, lane, DEL);  // prev ab-readers done (prev sync3)
      __syncthreads();                         // sync2: DEL visible
      {
        f32x4 acc[2][2] = {{zero4(), zero4()}, {zero4(), zero4()}};
        gemmG<256, 512>(smem + TMPB_OFF, wabA, wabB, lane, acc);
        char* dst = smem + (n - 1) * SLOT;
        const char* prv = smem + n * SLOT;     // l[n+1] (unused when n==8)
        #pragma unroll
        for (int q = 0; q < 16; ++q) {
          const int row = ((q >> 3) & 1) * 16 + kg * 4 + (q & 3);
          const int col = ((q >> 2) & 1) ? colB : colA;
          const int off = row * 512 + ((col * 2) ^ ((row & 7) << 4));
          float lp = 0.f;
          if (n < 8) lp = (float)(*(const f16*)(prv + off));
          *(f16*)(dst + off) = (f16)(lp + ACCQ(acc, q) + (((q >> 2) & 1) ? bab1 : bab0));
        }
      }
      __syncthreads();                         // sync3: l[n] visible
    }
    // ================= ascending gas sweep =================
    const int nmax = (sweep == 0) ? 7 : 8;     // sweep-0 g[8] is dead
    #pragma unroll 1
    for (int n = 1; n <= nmax; ++n) {
      float Gv[16];
      switch (n) {
        case 1: GH_READ(0, Gv); break;
        case 2: GH_READ(1, Gv); break;
        case 3: GH_READ(2, Gv); break;
        case 4: GH_READ(3, Gv); break;
        case 5: GH_READ(4, Gv); break;
        case 6: GH_READ(5, Gv); break;
        case 7: GH_READ(6, Gv); break;
        default: GH_READ(7, Gv); break;
      }
      float DF[16];
      {
        f32x4 acc[2][2] = {{zero4(), zero4()}, {zero4(), zero4()}};
        gemmG<256, 512>(smem + (n - 1) * SLOT, weqA, weqB, lane, acc);
        #pragma unroll
        for (int q = 0; q < 16; ++q)
          DF[q] = Gv[q] - sigm(ACCQ(acc, q) + (((q >> 2) & 1) ? beq1 : beq0));
      }
      store16(smem + TMPA_OFF, w, lane, DF);   // prev tr-readers done (trailing sync)
      __syncthreads();                         // DF visible
      float DEL[16];
      {
        f32x4 acc[2][2] = {{zero4(), zero4()}, {zero4(), zero4()}};
        gemmG<256, 512>(smem + TMPA_OFF, wtrA, wtrB, lane, acc);
        #pragma unroll
        for (int q = 0; q < 16; ++q)
          DEL[q] = alpha * (ACCQ(acc, q) + (((q >> 2) & 1) ? btr1 : btr0));
      }
      if (n < 8) {
        float NV[16];
        #pragma unroll
        for (int q = 0; q < 16; ++q) NV[q] = Gv[q] - DEL[q];
        switch (n) {
          case 1: GH_WRITE(1, NV); break;
          case 2: GH_WRITE(2, NV); break;
          case 3: GH_WRITE(3, NV); break;
          case 4: GH_WRITE(4, NV); break;
          case 5: GH_WRITE(5, NV); break;
          case 6: GH_WRITE(6, NV); break;
          default: GH_WRITE(7, NV); break;
        }
      } else {
        #pragma unroll
        for (int q = 0; q < 16; ++q) G8[q] = Gv[q] - DEL[q];
      }
      __syncthreads();                         // tr-readers of tmpA done
    }
  }

  // ---- head: feats = [g8 | l1] ----
  store16(smem + TMPA_OFF, w, lane, G8);       // tmpA free (trailing sync above)
  __syncthreads();
  {
    f32x4 acc[2][2] = {{zero4(), zero4()}, {zero4(), zero4()}};
    const int sw = (l15 & 7) << 4;
    const f16* w1A = W1T + (size_t)colA * 512 + kg * 8;
    const f16* w1B = W1T + (size_t)colB * 512 + kg * 8;
    #pragma unroll
    for (int ks = 0; ks < 16; ++ks) {
      const int kk = (ks << 5) + (kg << 3);
      const char* base = (kk < 256) ? (smem + TMPA_OFF) : smem;  // g8 | l[1]
      const int kl = (kk < 256) ? kk : (kk - 256);
      f16x8 a0 = *(const f16x8*)(base + l15 * 512 + ((kl * 2) ^ sw));
      f16x8 a1 = *(const f16x8*)(base + (16 + l15) * 512 + ((kl * 2) ^ sw));
      f16x8 b0 = *(const f16x8*)(w1A + (ks << 5));
      f16x8 b1 = *(const f16x8*)(w1B + (ks << 5));
      acc[0][0] = mfma16(a0, b0, acc[0][0]);
      acc[1][0] = mfma16(a1, b0, acc[1][0]);
      acc[0][1] = mfma16(a0, b1, acc[0][1]);
      acc[1][1] = mfma16(a1, b1, acc[1][1]);
    }
    const float bv0 = b1p[colA], bv1 = b1p[colB];
    float H[16];
    #pragma unroll
    for (int q = 0; q < 16; ++q) {
      float v2 = ACCQ(acc, q) + (((q >> 2) & 1) ? bv1 : bv0);
      H[q] = v2 > 0.f ? v2 : 0.f;
    }
    store16(smem + SLOT, w, lane, H);          // slot1 (disjoint from GEMM1 reads)
  }
  __syncthreads();

  // ---- out = h @ W2 + b2 into registers (63 col-frags over 8 waves) ----
  f32x4 cf0[8], cf1[8];
  {
    const int sw = (l15 & 7) << 4;
    #pragma unroll
    for (int fi = 0; fi < 8; ++fi) {
      const int f = w + fi * 8;
      cf0[fi] = zero4(); cf1[fi] = zero4();
      if (f < 63) {
        const f16* w2p = W2T + (size_t)(f * 16 + l15) * 256 + kg * 8;
        #pragma unroll
        for (int ks = 0; ks < 8; ++ks) {
          const int kk = (ks << 5) + (kg << 3);
          f16x8 a0 = *(const f16x8*)(smem + SLOT + l15 * 512 + ((kk * 2) ^ sw));
          f16x8 a1 = *(const f16x8*)(smem + SLOT + (16 + l15) * 512 + ((kk * 2) ^ sw));
          f16x8 b = *(const f16x8*)(w2p + (ks << 5));
          cf0[fi] = mfma16(a0, b, cf0[fi]);
          cf1[fi] = mfma16(a1, b, cf1[fi]);
        }
      }
    }
  }
  __syncthreads();  // all reads of slot1 done; slots become out staging

  // ---- stage out tile [32][1000] f32 in LDS, then coalesced copy ----
  {
    float* ob = (float*)smem;
    #pragma unroll
    for (int fi = 0; fi < 8; ++fi) {
      const int f = w + fi * 8;
      const int col = f * 16 + l15;
      if (f < 63 && col < 1000) {
        const float bv = b2p[col];
        #pragma unroll
        for (int j = 0; j < 4; ++j) {
          ob[(kg * 4 + j) * 1000 + col] = cf0[fi][j] + bv;
          ob[(16 + kg * 4 + j) * 1000 + col] = cf1[fi][j] + bv;
        }
      }
    }
  }
  __syncthreads();
  {
    const float* ob = (const float*)smem;
    float* op = out + (size_t)r0 * 1000;
    #pragma unroll 1
    for (int i = tid; i < 8000; i += NT) {
      float4 v = *(const float4*)(ob + i * 4);
      *(float4*)(op + i * 4) = v;
    }
  }
}

extern "C" void kernel_launch(void* const* d_in, const int* in_sizes, int n_in,
                              void* d_out, int out_size, void* d_ws, size_t ws_size,
                              hipStream_t stream) {
  const float* x   = (const float*)d_in[0];
  const float* Wge = (const float*)d_in[1];
  const float* bge = (const float*)d_in[2];
  const float* Weq = (const float*)d_in[3];
  const float* beq = (const float*)d_in[4];
  const float* Wtr = (const float*)d_in[5];
  const float* btr = (const float*)d_in[6];
  const float* Wab = (const float*)d_in[7];
  const float* bab = (const float*)d_in[8];
  const float* alp = (const float*)d_in[9];
  const float* W1  = (const float*)d_in[10];
  const float* b1  = (const float*)d_in[11];
  const float* W2  = (const float*)d_in[12];
  const float* b2  = (const float*)d_in[13];
  float* out = (float*)d_out;

  char* ws = (char*)d_ws;
  f16* WgeT = (f16*)(ws + 0);        // 256 x 512
  f16* WeqT = (f16*)(ws + 262144);   // 256 x 256
  f16* WtrT = (f16*)(ws + 393216);   // 256 x 256
  f16* WabT = (f16*)(ws + 524288);   // 256 x 256
  f16* W1T  = (f16*)(ws + 655360);   // 256 x 512
  f16* W2T  = (f16*)(ws + 917504);   // 1008 x 256 (rows >=1000 zero)

  prep_transpose<<<dim3(16, 8), 256, 0, stream>>>(Wge, WgeT, 512, 256, 256);
  prep_transpose<<<dim3(8, 8), 256, 0, stream>>>(Weq, WeqT, 256, 256, 256);
  prep_transpose<<<dim3(8, 8), 256, 0, stream>>>(Wtr, WtrT, 256, 256, 256);
  prep_transpose<<<dim3(8, 8), 256, 0, stream>>>(Wab, WabT, 256, 256, 256);
  prep_transpose<<<dim3(16, 8), 256, 0, stream>>>(W1, W1T, 512, 256, 256);
  prep_transpose<<<dim3(8, 32), 256, 0, stream>>>(W2, W2T, 256, 1000, 1008);

  (void)hipFuncSetAttribute(reinterpret_cast<const void*>(cfn_main),
                            hipFuncAttributeMaxDynamicSharedMemorySize, LDS_BYTES);
  cfn_main<<<16384 / TILE_B, NT, LDS_BYTES, stream>>>(
      x, bge, beq, btr, bab, alp, b1, b2,
      WgeT, WeqT, WtrT, WabT, W1T, W2T, out);
}

// Round 5
// 799.341 us; speedup vs baseline: 1.7470x; 1.3574x over previous
//
#include <hip/hip_runtime.h>

// CounterFlowNetwork fused kernel for MI355X (gfx950), round 5.
// R4 post-mortem: correctness bug was in the FUSED PREP ONLY — W2 Npad=1008
// gave bnT=floor(1008/32)=31: cols 992..1007 of W2T never written (poison ->
// absmax 1.995 on out cols 992..999) and ti>=248 wrapped bk past K, zeroing
// parts of W2T rows 1..32. Fix: pad W2T to 1024 rows (32 tiles exactly).
// Main kernel unchanged from R4 so its structure finally gets evaluated:
//   - NT=256 (4 waves, 1 wave/EU at 1 block/CU) -> full 512-reg budget.
//   - TILE_B=16; gas AND liquid state in LDS (18 x 8KB slots = 144 KB).
//   - W_eq/W_tr slices cached in VGPRs (128+128); W_ab/W_ge/W1/W2 from L2.

typedef _Float16 f16;
typedef _Float16 f16x8 __attribute__((ext_vector_type(8)));
typedef float f32x4 __attribute__((ext_vector_type(4)));

#define NT 256
#define TILE_B 16
#define SLOT 8192              // one [16][256] f16 slot
#define TMPA_OFF 131072        // slot 16
#define TMPB_OFF 139264        // slot 17
#define LDS_BYTES 147456       // 18 * 8192 = 144 KiB
#define GASP(s) (smem + (s) * SLOT)                 // g[0..7]: slots 0..7
#define LIQP(m) (smem + 57344 + (m) * SLOT)         // l[1..8]: slots 8..15

__device__ __forceinline__ f32x4 mfma16(f16x8 a, f16x8 b, f32x4 c) {
  return __builtin_amdgcn_mfma_f32_16x16x32_f16(a, b, c, 0, 0, 0);
}
__device__ __forceinline__ f32x4 zero4() {
  f32x4 z; z[0] = 0.f; z[1] = 0.f; z[2] = 0.f; z[3] = 0.f; return z;
}
__device__ __forceinline__ float sigm(float s) { return 1.f / (1.f + __expf(-s)); }

// A [16 x 256] f16 in LDS (512B rows, XOR-swizzled); B cached in regs.
__device__ __forceinline__ void gemm_rB(const char* aB, const f16x8 (&B)[8][4],
                                        int l15, int kg, f32x4 (&acc)[4]) {
  const int sw = (l15 & 7) << 4;
  #pragma unroll
  for (int ks = 0; ks < 8; ++ks) {
    const int kk = (ks << 5) + (kg << 3);
    f16x8 a = *(const f16x8*)(aB + l15 * 512 + ((kk * 2) ^ sw));
    #pragma unroll
    for (int f = 0; f < 4; ++f) acc[f] = mfma16(a, B[ks][f], acc[f]);
  }
}

// A [16 x K] f16 in LDS (stride AS); B streamed from global, 4 frag pointers
// (pre-offset by +kg*8).
template <int K, int AS>
__device__ __forceinline__ void gemm_gB(const char* aB,
                                        const f16* __restrict__ p0,
                                        const f16* __restrict__ p1,
                                        const f16* __restrict__ p2,
                                        const f16* __restrict__ p3,
                                        int l15, int kg, f32x4 (&acc)[4]) {
  const int sw = (l15 & 7) << 4;
  #pragma unroll
  for (int ks = 0; ks < (K >> 5); ++ks) {
    const int kk = (ks << 5) + (kg << 3);
    f16x8 a = *(const f16x8*)(aB + l15 * AS + ((kk * 2) ^ sw));
    acc[0] = mfma16(a, *(const f16x8*)(p0 + (ks << 5)), acc[0]);
    acc[1] = mfma16(a, *(const f16x8*)(p1 + (ks << 5)), acc[1]);
    acc[2] = mfma16(a, *(const f16x8*)(p2 + (ks << 5)), acc[2]);
    acc[3] = mfma16(a, *(const f16x8*)(p3 + (ks << 5)), acc[3]);
  }
}

// write/read 16 C-frag values (f=q>>2, j=q&3 -> row kg*4+j, col w*64+f*16+l15)
__device__ __forceinline__ void store16(char* buf, int w, int l15, int kg,
                                        const float* v) {
  #pragma unroll
  for (int q = 0; q < 16; ++q) {
    const int r = kg * 4 + (q & 3);
    const int c = w * 64 + ((q >> 2) << 4) + l15;
    *(f16*)(buf + r * 512 + ((c * 2) ^ ((r & 7) << 4))) = (f16)v[q];
  }
}
__device__ __forceinline__ void read16(const char* buf, int w, int l15, int kg,
                                       float* v) {
  #pragma unroll
  for (int q = 0; q < 16; ++q) {
    const int r = kg * 4 + (q & 3);
    const int c = w * 64 + ((q >> 2) << 4) + l15;
    v[q] = (float)*(const f16*)(buf + r * 512 + ((c * 2) ^ ((r & 7) << 4)));
  }
}

// One fused prep: all six [K][N] f32 -> [Npad][K] f16 transposes.
// Npad MUST be a multiple of 32 (tile math floor-divides otherwise — R4 bug).
__global__ void prep_all(const float* __restrict__ Wge, const float* __restrict__ Weq,
                         const float* __restrict__ Wtr, const float* __restrict__ Wab,
                         const float* __restrict__ W1,  const float* __restrict__ W2,
                         f16* __restrict__ WgeT, f16* __restrict__ WeqT,
                         f16* __restrict__ WtrT, f16* __restrict__ WabT,
                         f16* __restrict__ W1T,  f16* __restrict__ W2T) {
  __shared__ float ts[32][33];
  const int b = blockIdx.x;
  const float* src; f16* dst; int K, N, Npad, ti;
  if (b < 128)      { src = Wge; dst = WgeT; K = 512; N = 256;  Npad = 256;  ti = b; }
  else if (b < 192) { src = Weq; dst = WeqT; K = 256; N = 256;  Npad = 256;  ti = b - 128; }
  else if (b < 256) { src = Wtr; dst = WtrT; K = 256; N = 256;  Npad = 256;  ti = b - 192; }
  else if (b < 320) { src = Wab; dst = WabT; K = 256; N = 256;  Npad = 256;  ti = b - 256; }
  else if (b < 448) { src = W1;  dst = W1T;  K = 512; N = 256;  Npad = 256;  ti = b - 320; }
  else              { src = W2;  dst = W2T;  K = 256; N = 1000; Npad = 1024; ti = b - 448; }
  const int bnT = Npad >> 5;                 // exact: all Npad are 32-multiples
  const int bk = (ti / bnT) << 5, bn = (ti % bnT) << 5;
  const int tx = threadIdx.x & 31, ty = threadIdx.x >> 5;  // 32 x 8
  #pragma unroll
  for (int i = 0; i < 32; i += 8) {
    const int k = bk + ty + i, n = bn + tx;
    ts[ty + i][tx] = (k < K && n < N) ? src[(size_t)k * N + n] : 0.f;
  }
  __syncthreads();
  #pragma unroll
  for (int i = 0; i < 32; i += 8) {
    const int n = bn + ty + i, k = bk + tx;
    if (n < Npad) dst[(size_t)n * K + k] = (f16)ts[tx][ty + i];
  }
}

__global__ __launch_bounds__(NT, 1)
void cfn_main(const float* __restrict__ x,
              const float* __restrict__ bge, const float* __restrict__ beq,
              const float* __restrict__ btr, const float* __restrict__ bab,
              const float* __restrict__ alphap,
              const float* __restrict__ b1p, const float* __restrict__ b2p,
              const f16* __restrict__ WgeT, const f16* __restrict__ WeqT,
              const f16* __restrict__ WtrT, const f16* __restrict__ WabT,
              const f16* __restrict__ W1T, const f16* __restrict__ W2T,
              float* __restrict__ out) {
  extern __shared__ char smem[];
  const int tid = threadIdx.x;
  const int lane = tid & 63;
  const int w = tid >> 6;                    // 0..3, wave owns cols w*64..w*64+63
  const int l15 = lane & 15, kg = lane >> 4;
  const int r0 = blockIdx.x * TILE_B;
  const float alpha = alphap[0];
  const int sw = (l15 & 7) << 4;

  // per-frag biases (f = 0..3 -> col w*64 + f*16 + l15)
  float beqv[4], btrv[4], babv[4], se[4];
  #pragma unroll
  for (int f = 0; f < 4; ++f) {
    const int c = w * 64 + f * 16 + l15;
    beqv[f] = beq[c]; btrv[f] = btr[c]; babv[f] = bab[c];
    se[f] = sigm(beqv[f]);                   // e for l[9]=0 shortcut
  }

  // ---- cache W_eq / W_tr column slices in registers (128 + 128 VGPRs) ----
  f16x8 WeqR[8][4], WtrR[8][4];
  #pragma unroll
  for (int f = 0; f < 4; ++f) {
    const int c = w * 64 + f * 16 + l15;
    const f16* pe = WeqT + (size_t)c * 256 + kg * 8;
    const f16* pt = WtrT + (size_t)c * 256 + kg * 8;
    #pragma unroll
    for (int ks = 0; ks < 8; ++ks) {
      WeqR[ks][f] = *(const f16x8*)(pe + (ks << 5));
      WtrR[ks][f] = *(const f16x8*)(pt + (ks << 5));
    }
  }

  // streamed W_ab frag pointers
  const f16* wab0 = WabT + (size_t)(w * 64 +  0 + l15) * 256 + kg * 8;
  const f16* wab1 = WabT + (size_t)(w * 64 + 16 + l15) * 256 + kg * 8;
  const f16* wab2 = WabT + (size_t)(w * 64 + 32 + l15) * 256 + kg * 8;
  const f16* wab3 = WabT + (size_t)(w * 64 + 48 + l15) * 256 + kg * 8;

  // ---- stage x tile -> LDS f16 [16][512] swizzled (overlaps gas slots 0..1)
  {
    const int row = tid >> 4;                // 0..15
    const int cb = (tid & 15) << 5;          // 0..480
    const int rs = (row & 7) << 4;
    const float* p = x + (size_t)(r0 + row) * 512 + cb;
    #pragma unroll
    for (int i = 0; i < 4; ++i) {
      float4 u = *(const float4*)(p + i * 8);
      float4 v = *(const float4*)(p + i * 8 + 4);
      f16x8 h;
      h[0] = (f16)u.x; h[1] = (f16)u.y; h[2] = (f16)u.z; h[3] = (f16)u.w;
      h[4] = (f16)v.x; h[5] = (f16)v.y; h[6] = (f16)v.z; h[7] = (f16)v.w;
      *(f16x8*)(smem + row * 1024 + (((cb + i * 8) * 2) ^ rs)) = h;
    }
  }
  __syncthreads();

  // ---- g0 = relu(x @ W_ge + b_ge), replicate into gas slots 0..7 ----
  {
    f32x4 acc[4] = {zero4(), zero4(), zero4(), zero4()};
    const f16* g0 = WgeT + (size_t)(w * 64 +  0 + l15) * 512 + kg * 8;
    const f16* g1 = WgeT + (size_t)(w * 64 + 16 + l15) * 512 + kg * 8;
    const f16* g2 = WgeT + (size_t)(w * 64 + 32 + l15) * 512 + kg * 8;
    const f16* g3 = WgeT + (size_t)(w * 64 + 48 + l15) * 512 + kg * 8;
    gemm_gB<512, 1024>(smem, g0, g1, g2, g3, l15, kg, acc);
    float G0[16];
    #pragma unroll
    for (int q = 0; q < 16; ++q) {
      const float bv = bge[w * 64 + ((q >> 2) << 4) + l15];
      float v2 = acc[q >> 2][q & 3] + bv;
      G0[q] = v2 > 0.f ? v2 : 0.f;
    }
    __syncthreads();                         // all x reads done; slots reusable
    #pragma unroll
    for (int s = 0; s < 8; ++s) store16(GASP(s), w, l15, kg, G0);
  }
  __syncthreads();

  float G8[16];

  #pragma unroll 1
  for (int sweep = 0; sweep < 2; ++sweep) {
    // ============== descending liquid sweep: n = 8..1 ==============
    #pragma unroll 1
    for (int n = 8; n >= 1; --n) {
      float GV[16];
      read16(GASP(n - 1), w, l15, kg, GV);
      float DF[16];
      if (n == 8) {                          // l[9] == 0 -> e = sigm(b_eq)
        #pragma unroll
        for (int q = 0; q < 16; ++q) DF[q] = GV[q] - se[q >> 2];
      } else {
        f32x4 acc[4] = {zero4(), zero4(), zero4(), zero4()};
        gemm_rB(LIQP(n + 1), WeqR, l15, kg, acc);
        #pragma unroll
        for (int q = 0; q < 16; ++q)
          DF[q] = GV[q] - sigm(acc[q >> 2][q & 3] + beqv[q >> 2]);
      }
      store16(smem + TMPA_OFF, w, l15, kg, DF);   // prev tr-readers barrier'd
      __syncthreads();
      float DEL[16];
      {
        f32x4 acc[4] = {zero4(), zero4(), zero4(), zero4()};
        gemm_rB(smem + TMPA_OFF, WtrR, l15, kg, acc);
        #pragma unroll
        for (int q = 0; q < 16; ++q)
          DEL[q] = alpha * (acc[q >> 2][q & 3] + btrv[q >> 2]);
      }
      store16(smem + TMPB_OFF, w, l15, kg, DEL);  // prev ab-readers barrier'd
      __syncthreads();
      {
        f32x4 acc[4] = {zero4(), zero4(), zero4(), zero4()};
        gemm_gB<256, 512>(smem + TMPB_OFF, wab0, wab1, wab2, wab3, l15, kg, acc);
        float LN[16];
        if (n < 8) read16(LIQP(n + 1), w, l15, kg, LN);
        else { _Pragma("unroll") for (int q = 0; q < 16; ++q) LN[q] = 0.f; }
        #pragma unroll
        for (int q = 0; q < 16; ++q)
          LN[q] += acc[q >> 2][q & 3] + babv[q >> 2];
        store16(LIQP(n), w, l15, kg, LN);
      }
      __syncthreads();                       // l[n] visible; tmpA/B reusable
    }
    // ============== ascending gas sweep: n = 1..nmax ==============
    const int nmax = (sweep == 0) ? 7 : 8;   // sweep-0 g[8] is dead
    #pragma unroll 1
    for (int n = 1; n <= nmax; ++n) {
      float GV[16];
      read16(GASP(n - 1), w, l15, kg, GV);
      float DF[16];
      {
        f32x4 acc[4] = {zero4(), zero4(), zero4(), zero4()};
        gemm_rB(LIQP(n), WeqR, l15, kg, acc);
        #pragma unroll
        for (int q = 0; q < 16; ++q)
          DF[q] = GV[q] - sigm(acc[q >> 2][q & 3] + beqv[q >> 2]);
      }
      store16(smem + TMPA_OFF, w, l15, kg, DF);   // prev readers barrier'd
      __syncthreads();
      {
        f32x4 acc[4] = {zero4(), zero4(), zero4(), zero4()};
        gemm_rB(smem + TMPA_OFF, WtrR, l15, kg, acc);
        if (n < 8) {
          float NG[16];
          #pragma unroll
          for (int q = 0; q < 16; ++q)
            NG[q] = GV[q] - alpha * (acc[q >> 2][q & 3] + btrv[q >> 2]);
          store16(GASP(n), w, l15, kg, NG);
        } else {
          #pragma unroll
          for (int q = 0; q < 16; ++q)
            G8[q] = GV[q] - alpha * (acc[q >> 2][q & 3] + btrv[q >> 2]);
        }
      }
      __syncthreads();                       // g[n] visible; tmpA reusable
    }
  }

  // ---- head: feats = [g8 | l1]; h = relu(feats @ W1 + b1) ----
  store16(smem + TMPA_OFF, w, l15, kg, G8);
  __syncthreads();
  {
    f32x4 acc[4] = {zero4(), zero4(), zero4(), zero4()};
    const f16* p0 = W1T + (size_t)(w * 64 +  0 + l15) * 512 + kg * 8;
    const f16* p1 = W1T + (size_t)(w * 64 + 16 + l15) * 512 + kg * 8;
    const f16* p2 = W1T + (size_t)(w * 64 + 32 + l15) * 512 + kg * 8;
    const f16* p3 = W1T + (size_t)(w * 64 + 48 + l15) * 512 + kg * 8;
    #pragma unroll
    for (int ks = 0; ks < 16; ++ks) {
      const int kk = (ks << 5) + (kg << 3);
      const char* base = (ks < 8) ? (smem + TMPA_OFF) : (smem + 65536); // g8|l1
      const int kl = kk & 255;
      f16x8 a = *(const f16x8*)(base + l15 * 512 + ((kl * 2) ^ sw));
      acc[0] = mfma16(a, *(const f16x8*)(p0 + (ks << 5)), acc[0]);
      acc[1] = mfma16(a, *(const f16x8*)(p1 + (ks << 5)), acc[1]);
      acc[2] = mfma16(a, *(const f16x8*)(p2 + (ks << 5)), acc[2]);
      acc[3] = mfma16(a, *(const f16x8*)(p3 + (ks << 5)), acc[3]);
    }
    float H[16];
    #pragma unroll
    for (int q = 0; q < 16; ++q) {
      const float bv = b1p[w * 64 + ((q >> 2) << 4) + l15];
      float v2 = acc[q >> 2][q & 3] + bv;
      H[q] = v2 > 0.f ? v2 : 0.f;
    }
    __syncthreads();
    store16(smem + TMPB_OFF, w, l15, kg, H);
  }
  __syncthreads();

  // ---- out = h @ W2 + b2 (63 col-frags over 4 waves) ----
  f32x4 cf[16];
  #pragma unroll
  for (int fi = 0; fi < 16; ++fi) {
    cf[fi] = zero4();
    const int f = w + fi * 4;
    if (f < 63) {
      const f16* p = W2T + (size_t)(f * 16 + l15) * 256 + kg * 8;
      #pragma unroll
      for (int ks = 0; ks < 8; ++ks) {
        const int kk = (ks << 5) + (kg << 3);
        f16x8 a = *(const f16x8*)(smem + TMPB_OFF + l15 * 512 + ((kk * 2) ^ sw));
        cf[fi] = mfma16(a, *(const f16x8*)(p + (ks << 5)), cf[fi]);
      }
    }
  }

  // ---- stage out tile [16][1000] f32 in gas-slot area, coalesced copy ----
  {
    float* ob = (float*)smem;                // slots 0..7 (64 KB) - gas is dead
    #pragma unroll
    for (int fi = 0; fi < 16; ++fi) {
      const int f = w + fi * 4;
      const int colc = f * 16 + l15;
      if (f < 63 && colc < 1000) {
        const float bv = b2p[colc];
        #pragma unroll
        for (int j = 0; j < 4; ++j)
          ob[(kg * 4 + j) * 1000 + colc] = cf[fi][j] + bv;
      }
    }
  }
  __syncthreads();
  {
    const float* ob = (const float*)smem;
    float* op = out + (size_t)r0 * 1000;
    #pragma unroll 1
    for (int i = tid; i < 4000; i += NT)
      *(float4*)(op + i * 4) = *(const float4*)(ob + i * 4);
  }
}

extern "C" void kernel_launch(void* const* d_in, const int* in_sizes, int n_in,
                              void* d_out, int out_size, void* d_ws, size_t ws_size,
                              hipStream_t stream) {
  const float* x   = (const float*)d_in[0];
  const float* Wge = (const float*)d_in[1];
  const float* bge = (const float*)d_in[2];
  const float* Weq = (const float*)d_in[3];
  const float* beq = (const float*)d_in[4];
  const float* Wtr = (const float*)d_in[5];
  const float* btr = (const float*)d_in[6];
  const float* Wab = (const float*)d_in[7];
  const float* bab = (const float*)d_in[8];
  const float* alp = (const float*)d_in[9];
  const float* W1  = (const float*)d_in[10];
  const float* b1  = (const float*)d_in[11];
  const float* W2  = (const float*)d_in[12];
  const float* b2  = (const float*)d_in[13];
  float* out = (float*)d_out;

  char* ws = (char*)d_ws;
  f16* WgeT = (f16*)(ws + 0);        // 256 x 512
  f16* WeqT = (f16*)(ws + 262144);   // 256 x 256
  f16* WtrT = (f16*)(ws + 393216);   // 256 x 256
  f16* WabT = (f16*)(ws + 524288);   // 256 x 256
  f16* W1T  = (f16*)(ws + 655360);   // 256 x 512
  f16* W2T  = (f16*)(ws + 917504);   // 1024 x 256 (rows >= 1000 zero)

  prep_all<<<704, 256, 0, stream>>>(Wge, Weq, Wtr, Wab, W1, W2,
                                    WgeT, WeqT, WtrT, WabT, W1T, W2T);

  (void)hipFuncSetAttribute(reinterpret_cast<const void*>(cfn_main),
                            hipFuncAttributeMaxDynamicSharedMemorySize, LDS_BYTES);
  cfn_main<<<16384 / TILE_B, NT, LDS_BYTES, stream>>>(
      x, bge, beq, btr, bab, alp, b1, b2,
      WgeT, WeqT, WtrT, WabT, W1T, W2T, out);
}